// Round 1
// 1015.945 us; speedup vs baseline: 1.2224x; 1.2224x over previous
//
#include <hip/hip_runtime.h>
#include <hip/hip_bf16.h>

#define T_DIM 1024
#define H_DIM 2048
#define F_DIM 4096
#define E_DIM 8

typedef unsigned short u16;
typedef unsigned int u32;
typedef __attribute__((ext_vector_type(8))) short bf16x8;
typedef __attribute__((ext_vector_type(4))) float f32x4;

// round-to-nearest-even fp32 -> bf16 (raw bits)
__device__ __forceinline__ u16 f2bf(float f) {
  u32 u = __builtin_bit_cast(u32, f);
  u32 r = (u + 0x7fffu + ((u >> 16) & 1u)) >> 16;
  return (u16)r;
}

// ---------------------------------------------------------------------------
// Kernel 1: gate logits + top-2 weights (exact reference emulation) + x->bf16
// grid: T/4 blocks x 256 threads; one wave per token.
// ---------------------------------------------------------------------------
__global__ __launch_bounds__(256) void gate_cvt_kernel(
    const float* __restrict__ x, const float* __restrict__ wg,
    u16* __restrict__ xb, float* __restrict__ wts) {
  int wave = threadIdx.x >> 6;
  int lane = threadIdx.x & 63;
  int t = blockIdx.x * 4 + wave;
  const float4* x4 = reinterpret_cast<const float4*>(x) + (size_t)t * 512;
  ushort4* xb4 = reinterpret_cast<ushort4*>(xb) + (size_t)t * 512;
  const float4* wg4 = reinterpret_cast<const float4*>(wg);

  float acc[8];
#pragma unroll
  for (int e = 0; e < 8; e++) acc[e] = 0.f;

#pragma unroll
  for (int i = 0; i < 8; i++) {
    int idx = i * 64 + lane;                 // float4 index within row (0..511)
    float4 v = x4[idx];
    ushort4 o = {f2bf(v.x), f2bf(v.y), f2bf(v.z), f2bf(v.w)};
    xb4[idx] = o;
    float xs[4] = {v.x, v.y, v.z, v.w};
    int hbase = idx * 4;
#pragma unroll
    for (int j = 0; j < 4; j++) {
      float4 wa = wg4[(hbase + j) * 2];
      float4 wb = wg4[(hbase + j) * 2 + 1];
      acc[0] += xs[j] * wa.x; acc[1] += xs[j] * wa.y;
      acc[2] += xs[j] * wa.z; acc[3] += xs[j] * wa.w;
      acc[4] += xs[j] * wb.x; acc[5] += xs[j] * wb.y;
      acc[6] += xs[j] * wb.z; acc[7] += xs[j] * wb.w;
    }
  }
  // wave-64 reduction per expert
#pragma unroll
  for (int e = 0; e < 8; e++) {
#pragma unroll
    for (int off = 32; off > 0; off >>= 1) acc[e] += __shfl_xor(acc[e], off, 64);
  }
  if (lane == 0) {
    const float NEG_MIN = -3.402823466e38f;
    float ex0 = acc[0];
#pragma unroll
    for (int e = 1; e < 8; e++) ex0 = fmaxf(ex0, acc[e]);
    float masked[8];
#pragma unroll
    for (int e = 0; e < 8; e++) masked[e] = (acc[e] == ex0) ? NEG_MIN : acc[e];
    float ex1 = masked[0];
#pragma unroll
    for (int e = 1; e < 8; e++) ex1 = fmaxf(ex1, masked[e]);
    float w0 = 1.f / (1.f + expf(ex1 - ex0));
#pragma unroll
    for (int e = 0; e < 8; e++) {
      float w = (acc[e] == ex0) ? w0 : ((masked[e] == ex1) ? (1.f - w0) : 0.f);
      wts[t * 8 + e] = w;
    }
  }
}

// ---------------------------------------------------------------------------
// Kernel 1b: deterministic per-expert token compaction.
// Experts with wts[t,e] != 0 contribute; zero-weight experts contribute an
// exact 0.0 in the reference, so skipping them is bit-identical.
// 1 block x 512 threads; wave e stream-compacts tokens in ascending order.
// ---------------------------------------------------------------------------
__global__ __launch_bounds__(512) void route_kernel(
    const float* __restrict__ wts, int* __restrict__ tlist,
    int* __restrict__ counts) {
  int e = threadIdx.x >> 6;
  int lane = threadIdx.x & 63;
  int base = 0;
  for (int c = 0; c < T_DIM; c += 64) {
    float w = wts[(c + lane) * 8 + e];
    unsigned long long m = __ballot(w != 0.f);
    if (w != 0.f) {
      int pos = base + __popcll(m & ((1ull << lane) - 1ull));
      tlist[e * T_DIM + pos] = c + lane;
    }
    base += __popcll(m);
  }
  if (lane == 0) counts[e] = base;
}

// ---------------------------------------------------------------------------
// Kernel 2: transpose + fp32->bf16.  src (R,C) fp32 row-major -> dst (C,R) bf16
// grid: (C/64, R/64, experts) x 256 threads.  64x64 tiles via LDS.
// ---------------------------------------------------------------------------
__global__ __launch_bounds__(256) void transpose_cvt_kernel(
    const float* __restrict__ src, u16* __restrict__ dst, int R, int C) {
  __shared__ u16 tile[64][68];   // +4 pad breaks bank alignment
  long eoff = (long)blockIdx.z * R * C;
  const float* s = src + eoff;
  u16* d = dst + eoff;
  int c0 = blockIdx.x * 64, r0 = blockIdx.y * 64;
  int tid = threadIdx.x;
#pragma unroll
  for (int p = 0; p < 4; p++) {
    int idx = tid + p * 256;
    int r = idx >> 4, c4 = (idx & 15) << 2;
    float4 v = *reinterpret_cast<const float4*>(s + (long)(r0 + r) * C + c0 + c4);
    ushort4 o = {f2bf(v.x), f2bf(v.y), f2bf(v.z), f2bf(v.w)};
    *reinterpret_cast<ushort4*>(&tile[r][c4]) = o;
  }
  __syncthreads();
#pragma unroll
  for (int p = 0; p < 4; p++) {
    int idx = tid + p * 256;
    int c = idx >> 4, r4 = (idx & 15) << 2;
    ushort4 o = {tile[r4][c], tile[r4 + 1][c], tile[r4 + 2][c], tile[r4 + 3][c]};
    *reinterpret_cast<ushort4*>(d + (long)(c0 + c) * R + r0 + r4) = o;
  }
}

// ---------------------------------------------------------------------------
// Kernel 3: h_e = silu(xg @ w1[e]) * (xg @ w3[e]), bf16 out, COMPACTED rows.
// A rows gathered via tlist (only tokens routed to expert e).  Blocks whose
// M-tile lies beyond counts[e] exit immediately.  Tail rows are clamped
// duplicates; their D rows are masked at the epilogue.
// ---------------------------------------------------------------------------
__global__ __launch_bounds__(256, 2) void h_kernel(
    const u16* __restrict__ xb, const u16* __restrict__ w1t,
    const u16* __restrict__ w3t, u16* __restrict__ hout,
    const int* __restrict__ tlist, const int* __restrict__ counts,
    int e_base) {
  int el = blockIdx.z;   // expert (group-local)
  int eg = e_base + el;
  int ne = counts[eg];
  int t0 = blockIdx.y * 128;
  if (t0 >= ne) return;

  __shared__ u16 As[128 * 72];
  __shared__ u16 B1s[64 * 72];
  __shared__ u16 B3s[64 * 72];
  __shared__ int toks[128];

  int f0 = blockIdx.x * 64;
  const u16* b1 = w1t + (long)el * F_DIM * H_DIM;
  const u16* b3 = w3t + (long)el * F_DIM * H_DIM;
  int tid = threadIdx.x;
  if (tid < 128) {
    int i = t0 + tid;
    toks[tid] = tlist[eg * T_DIM + (i < ne ? i : ne - 1)];
  }
  __syncthreads();

  int wave = tid >> 6, lane = tid & 63;
  int wm = wave >> 1, wn = wave & 1;
  int mrow = lane & 15, quad = lane >> 4;

  // hoist gathered row pointers out of the K-loop
  const u16* aptr[4];
  int aoff[4];
#pragma unroll
  for (int it = 0; it < 4; it++) {
    int chunk = tid + it * 256;
    int r = chunk >> 3, c8 = (chunk & 7) << 3;
    aptr[it] = xb + (long)toks[r] * H_DIM + c8;
    aoff[it] = r * 72 + c8;
  }

  f32x4 acc1[4][2], acc3[4][2];
#pragma unroll
  for (int mt = 0; mt < 4; mt++)
#pragma unroll
    for (int nt = 0; nt < 2; nt++) { acc1[mt][nt] = (f32x4)(0.f); acc3[mt][nt] = (f32x4)(0.f); }

  for (int kt = 0; kt < H_DIM; kt += 64) {
    // stage A: 128x64 bf16, rows gathered
#pragma unroll
    for (int it = 0; it < 4; it++) {
      uint4 v = *reinterpret_cast<const uint4*>(aptr[it] + kt);
      *reinterpret_cast<uint4*>(&As[aoff[it]]) = v;
    }
    // stage B1/B3: 64x64 bf16 each
#pragma unroll
    for (int it = 0; it < 2; it++) {
      int chunk = tid + it * 256;
      int r = chunk >> 3, c8 = (chunk & 7) << 3;
      long off = (long)(f0 + r) * H_DIM + kt + c8;
      uint4 v1 = *reinterpret_cast<const uint4*>(b1 + off);
      uint4 v3 = *reinterpret_cast<const uint4*>(b3 + off);
      *reinterpret_cast<uint4*>(&B1s[r * 72 + c8]) = v1;
      *reinterpret_cast<uint4*>(&B3s[r * 72 + c8]) = v3;
    }
    __syncthreads();
#pragma unroll
    for (int kh = 0; kh < 2; kh++) {
      int koff = kh * 32 + quad * 8;
      bf16x8 af[4], b1f[2], b3f[2];
#pragma unroll
      for (int mt = 0; mt < 4; mt++)
        af[mt] = *reinterpret_cast<const bf16x8*>(&As[(wm * 64 + mt * 16 + mrow) * 72 + koff]);
#pragma unroll
      for (int nt = 0; nt < 2; nt++) {
        b1f[nt] = *reinterpret_cast<const bf16x8*>(&B1s[(wn * 32 + nt * 16 + mrow) * 72 + koff]);
        b3f[nt] = *reinterpret_cast<const bf16x8*>(&B3s[(wn * 32 + nt * 16 + mrow) * 72 + koff]);
      }
#pragma unroll
      for (int mt = 0; mt < 4; mt++)
#pragma unroll
        for (int nt = 0; nt < 2; nt++) {
          acc1[mt][nt] = __builtin_amdgcn_mfma_f32_16x16x32_bf16(af[mt], b1f[nt], acc1[mt][nt], 0, 0, 0);
          acc3[mt][nt] = __builtin_amdgcn_mfma_f32_16x16x32_bf16(af[mt], b3f[nt], acc3[mt][nt], 0, 0, 0);
        }
    }
    __syncthreads();
  }
  // epilogue: SwiGLU, write bf16 to COMPACT rows.  Mask rows >= ne.
  u16* hp = hout + (long)el * T_DIM * F_DIM;
#pragma unroll
  for (int mt = 0; mt < 4; mt++) {
#pragma unroll
    for (int r = 0; r < 4; r++) {
      int row = t0 + wm * 64 + mt * 16 + quad * 4 + r;
      if (row < ne) {
#pragma unroll
        for (int nt = 0; nt < 2; nt++) {
          int col = f0 + wn * 32 + nt * 16 + mrow;
          float v1 = acc1[mt][nt][r];
          float v3 = acc3[mt][nt][r];
          float sw = (v1 / (1.f + expf(-v1))) * v3;
          hp[(long)row * F_DIM + col] = f2bf(sw);
        }
      }
    }
  }
}

// ---------------------------------------------------------------------------
// Kernel 4: out[tok,hh] += wts[tok,e] * (h_e @ w2[e])[row,hh], rows compact.
// A = compact h_e; epilogue scatter-adds to the token's output row.
// ---------------------------------------------------------------------------
__global__ __launch_bounds__(256, 2) void y_kernel(
    const u16* __restrict__ h, const u16* __restrict__ w2t,
    const float* __restrict__ wts, float* __restrict__ out,
    const int* __restrict__ tlist, const int* __restrict__ counts,
    int e_base) {
  int el = blockIdx.z;
  int eg = e_base + el;
  int ne = counts[eg];
  int t0 = blockIdx.y * 128;
  if (t0 >= ne) return;

  __shared__ u16 As[128 * 72];
  __shared__ u16 Bs[64 * 72];
  int n0 = blockIdx.x * 64;
  const u16* a = h + (long)el * T_DIM * F_DIM;
  const u16* b = w2t + (long)el * H_DIM * F_DIM;
  int tid = threadIdx.x;
  int wave = tid >> 6, lane = tid & 63;
  int wm = wave >> 1, wn = wave & 1;
  int mrow = lane & 15, quad = lane >> 4;

  f32x4 acc[4][2];
#pragma unroll
  for (int mt = 0; mt < 4; mt++)
#pragma unroll
    for (int nt = 0; nt < 2; nt++) acc[mt][nt] = (f32x4)(0.f);

  for (int kt = 0; kt < F_DIM; kt += 64) {
#pragma unroll
    for (int it = 0; it < 4; it++) {
      int chunk = tid + it * 256;
      int r = chunk >> 3, c8 = (chunk & 7) << 3;
      uint4 v = *reinterpret_cast<const uint4*>(a + (long)(t0 + r) * F_DIM + kt + c8);
      *reinterpret_cast<uint4*>(&As[r * 72 + c8]) = v;
    }
#pragma unroll
    for (int it = 0; it < 2; it++) {
      int chunk = tid + it * 256;
      int r = chunk >> 3, c8 = (chunk & 7) << 3;
      uint4 v = *reinterpret_cast<const uint4*>(b + (long)(n0 + r) * F_DIM + kt + c8);
      *reinterpret_cast<uint4*>(&Bs[r * 72 + c8]) = v;
    }
    __syncthreads();
#pragma unroll
    for (int kh = 0; kh < 2; kh++) {
      int koff = kh * 32 + quad * 8;
      bf16x8 af[4], bf[2];
#pragma unroll
      for (int mt = 0; mt < 4; mt++)
        af[mt] = *reinterpret_cast<const bf16x8*>(&As[(wm * 64 + mt * 16 + mrow) * 72 + koff]);
#pragma unroll
      for (int nt = 0; nt < 2; nt++)
        bf[nt] = *reinterpret_cast<const bf16x8*>(&Bs[(wn * 32 + nt * 16 + mrow) * 72 + koff]);
#pragma unroll
      for (int mt = 0; mt < 4; mt++)
#pragma unroll
        for (int nt = 0; nt < 2; nt++)
          acc[mt][nt] = __builtin_amdgcn_mfma_f32_16x16x32_bf16(af[mt], bf[nt], acc[mt][nt], 0, 0, 0);
    }
    __syncthreads();
  }
#pragma unroll
  for (int mt = 0; mt < 4; mt++) {
#pragma unroll
    for (int r = 0; r < 4; r++) {
      int row = t0 + wm * 64 + mt * 16 + quad * 4 + r;
      if (row < ne) {
        int tok = tlist[eg * T_DIM + row];
        float wt = wts[tok * 8 + eg];
#pragma unroll
        for (int nt = 0; nt < 2; nt++) {
          int col = n0 + wn * 32 + nt * 16 + mrow;
          unsafeAtomicAdd(&out[(long)tok * H_DIM + col], acc[mt][nt][r] * wt);
        }
      }
    }
  }
}

// ---------------------------------------------------------------------------
extern "C" void kernel_launch(void* const* d_in, const int* in_sizes, int n_in,
                              void* d_out, int out_size, void* d_ws, size_t ws_size,
                              hipStream_t stream) {
  const float* x  = (const float*)d_in[0];
  const float* wg = (const float*)d_in[1];
  const float* w1 = (const float*)d_in[2];
  const float* w3 = (const float*)d_in[3];
  const float* w2 = (const float*)d_in[4];
  float* out = (float*)d_out;

  char* p = (char*)d_ws;
  u16* xb = (u16*)p;            p += (size_t)T_DIM * H_DIM * 2;
  float* wts = (float*)p;       p += (size_t)T_DIM * E_DIM * 4;
  int* tlist = (int*)p;         p += (size_t)E_DIM * T_DIM * 4;
  int* counts = (int*)p;        p += 256;
  size_t fixed = (size_t)(p - (char*)d_ws);
  size_t perE = (size_t)F_DIM * H_DIM * 2 * 3 + (size_t)T_DIM * F_DIM * 2;
  int G = 1;
  for (int g = 8; g >= 1; g >>= 1) {
    if (fixed + (size_t)g * perE <= ws_size) { G = g; break; }
  }
  u16* w1t = (u16*)p;           p += (size_t)G * F_DIM * H_DIM * 2;
  u16* w3t = (u16*)p;           p += (size_t)G * F_DIM * H_DIM * 2;
  u16* w2t = (u16*)p;           p += (size_t)G * H_DIM * F_DIM * 2;
  u16* hbuf = (u16*)p;

  gate_cvt_kernel<<<T_DIM / 4, 256, 0, stream>>>(x, wg, xb, wts);
  route_kernel<<<1, 512, 0, stream>>>(wts, tlist, counts);
  hipMemsetAsync(d_out, 0, (size_t)out_size * 4, stream);

  for (int e0 = 0; e0 < E_DIM; e0 += G) {
    transpose_cvt_kernel<<<dim3(F_DIM / 64, H_DIM / 64, G), 256, 0, stream>>>(
        w1 + (size_t)e0 * H_DIM * F_DIM, w1t, H_DIM, F_DIM);
    transpose_cvt_kernel<<<dim3(F_DIM / 64, H_DIM / 64, G), 256, 0, stream>>>(
        w3 + (size_t)e0 * H_DIM * F_DIM, w3t, H_DIM, F_DIM);
    transpose_cvt_kernel<<<dim3(H_DIM / 64, F_DIM / 64, G), 256, 0, stream>>>(
        w2 + (size_t)e0 * F_DIM * H_DIM, w2t, F_DIM, H_DIM);
    h_kernel<<<dim3(F_DIM / 64, T_DIM / 128, G), 256, 0, stream>>>(
        xb, w1t, w3t, hbuf, tlist, counts, e0);
    y_kernel<<<dim3(H_DIM / 64, T_DIM / 128, G), 256, 0, stream>>>(
        hbuf, w2t, wts, out, tlist, counts, e0);
  }
}

// Round 2
// 900.879 us; speedup vs baseline: 1.3785x; 1.1277x over previous
//
#include <hip/hip_runtime.h>
#include <hip/hip_bf16.h>

#define T_DIM 1024
#define H_DIM 2048
#define F_DIM 4096
#define E_DIM 8

typedef unsigned short u16;
typedef unsigned int u32;
typedef __attribute__((ext_vector_type(8))) short bf16x8;
typedef __attribute__((ext_vector_type(4))) float f32x4;

// round-to-nearest-even fp32 -> bf16 (raw bits)
__device__ __forceinline__ u16 f2bf(float f) {
  u32 u = __builtin_bit_cast(u32, f);
  u32 r = (u + 0x7fffu + ((u >> 16) & 1u)) >> 16;
  return (u16)r;
}

// ---------------------------------------------------------------------------
// Kernel 1: gate logits + top-2 weights (exact reference emulation) + x->bf16
// ---------------------------------------------------------------------------
__global__ __launch_bounds__(256) void gate_cvt_kernel(
    const float* __restrict__ x, const float* __restrict__ wg,
    u16* __restrict__ xb, float* __restrict__ wts) {
  int wave = threadIdx.x >> 6;
  int lane = threadIdx.x & 63;
  int t = blockIdx.x * 4 + wave;
  const float4* x4 = reinterpret_cast<const float4*>(x) + (size_t)t * 512;
  ushort4* xb4 = reinterpret_cast<ushort4*>(xb) + (size_t)t * 512;
  const float4* wg4 = reinterpret_cast<const float4*>(wg);

  float acc[8];
#pragma unroll
  for (int e = 0; e < 8; e++) acc[e] = 0.f;

#pragma unroll
  for (int i = 0; i < 8; i++) {
    int idx = i * 64 + lane;
    float4 v = x4[idx];
    ushort4 o = {f2bf(v.x), f2bf(v.y), f2bf(v.z), f2bf(v.w)};
    xb4[idx] = o;
    float xs[4] = {v.x, v.y, v.z, v.w};
    int hbase = idx * 4;
#pragma unroll
    for (int j = 0; j < 4; j++) {
      float4 wa = wg4[(hbase + j) * 2];
      float4 wb = wg4[(hbase + j) * 2 + 1];
      acc[0] += xs[j] * wa.x; acc[1] += xs[j] * wa.y;
      acc[2] += xs[j] * wa.z; acc[3] += xs[j] * wa.w;
      acc[4] += xs[j] * wb.x; acc[5] += xs[j] * wb.y;
      acc[6] += xs[j] * wb.z; acc[7] += xs[j] * wb.w;
    }
  }
#pragma unroll
  for (int e = 0; e < 8; e++) {
#pragma unroll
    for (int off = 32; off > 0; off >>= 1) acc[e] += __shfl_xor(acc[e], off, 64);
  }
  if (lane == 0) {
    const float NEG_MIN = -3.402823466e38f;
    float ex0 = acc[0];
#pragma unroll
    for (int e = 1; e < 8; e++) ex0 = fmaxf(ex0, acc[e]);
    float masked[8];
#pragma unroll
    for (int e = 0; e < 8; e++) masked[e] = (acc[e] == ex0) ? NEG_MIN : acc[e];
    float ex1 = masked[0];
#pragma unroll
    for (int e = 1; e < 8; e++) ex1 = fmaxf(ex1, masked[e]);
    float w0 = 1.f / (1.f + expf(ex1 - ex0));
#pragma unroll
    for (int e = 0; e < 8; e++) {
      float w = (acc[e] == ex0) ? w0 : ((masked[e] == ex1) ? (1.f - w0) : 0.f);
      wts[t * 8 + e] = w;
    }
  }
}

// ---------------------------------------------------------------------------
// Kernel 1b: deterministic per-expert token compaction (top-2 => wts!=0).
// ---------------------------------------------------------------------------
__global__ __launch_bounds__(512) void route_kernel(
    const float* __restrict__ wts, int* __restrict__ tlist,
    int* __restrict__ counts) {
  int e = threadIdx.x >> 6;
  int lane = threadIdx.x & 63;
  int base = 0;
  for (int c = 0; c < T_DIM; c += 64) {
    float w = wts[(c + lane) * 8 + e];
    unsigned long long m = __ballot(w != 0.f);
    if (w != 0.f) {
      int pos = base + __popcll(m & ((1ull << lane) - 1ull));
      tlist[e * T_DIM + pos] = c + lane;
    }
    base += __popcll(m);
  }
  if (lane == 0) counts[e] = base;
}

// ---------------------------------------------------------------------------
// Kernel 2: h_e = silu(xg @ w1[e]) * (xg @ w3[e]), bf16 out, compacted rows.
// Weights read in NATIVE fp32 (H,F) layout; transpose+cvt fused into LDS
// staging: per thread load 4 K-rows x 4 N-cols fp32 coalesced, pack 4 K into
// b64 per column, write at f*72 + (k ^ (((f>>2)&7)<<3)).  The slot-XOR (16B
// granular) makes packed writes 2-way bank-free and keeps b128 reads aligned;
// reads apply the same XOR.
// ---------------------------------------------------------------------------
__global__ __launch_bounds__(256, 2) void h_kernel(
    const u16* __restrict__ xb, const float* __restrict__ w1,
    const float* __restrict__ w3, u16* __restrict__ hout,
    const int* __restrict__ tlist, const int* __restrict__ counts) {
  int el = blockIdx.z;
  int ne = counts[el];
  int t0 = blockIdx.y * 128;
  if (t0 >= ne) return;

  __shared__ u16 As[128 * 72];
  __shared__ u16 B1s[64 * 72];
  __shared__ u16 B3s[64 * 72];
  __shared__ int toks[128];

  int f0 = blockIdx.x * 64;
  const float* b1 = w1 + (long)el * H_DIM * F_DIM;
  const float* b3 = w3 + (long)el * H_DIM * F_DIM;
  int tid = threadIdx.x;
  if (tid < 128) {
    int i = t0 + tid;
    toks[tid] = tlist[el * T_DIM + (i < ne ? i : ne - 1)];
  }
  __syncthreads();

  int wave = tid >> 6, lane = tid & 63;
  int wm = wave >> 1, wn = wave & 1;
  int mrow = lane & 15, quad = lane >> 4;

  // A: gathered token rows (bf16, K-contiguous), hoisted out of K-loop
  const u16* aptr[4];
  int aoff[4];
#pragma unroll
  for (int it = 0; it < 4; it++) {
    int chunk = tid + it * 256;
    int r = chunk >> 3, c8 = (chunk & 7) << 3;
    aptr[it] = xb + (long)toks[r] * H_DIM + c8;
    aoff[it] = r * 72 + c8;
  }

  // B transposed staging coords: thread owns cols f4..f4+3, k-rows bk0..bk0+3
  int bf4 = (tid & 15) << 2;
  int bk0 = (tid >> 4) << 2;
  int bwoff[4];
#pragma unroll
  for (int j = 0; j < 4; j++) {
    int f = bf4 + j;
    bwoff[j] = f * 72 + (bk0 ^ (((f >> 2) & 7) << 3));
  }
  const float* gb1 = b1 + (long)bk0 * F_DIM + f0 + bf4;
  const float* gb3 = b3 + (long)bk0 * F_DIM + f0 + bf4;

  // fragment read offsets (precomputed; XOR on B side only)
  int aroff[4][2], broff[2][2];
#pragma unroll
  for (int mt = 0; mt < 4; mt++)
#pragma unroll
    for (int kh = 0; kh < 2; kh++)
      aroff[mt][kh] = (wm * 64 + mt * 16 + mrow) * 72 + kh * 32 + quad * 8;
#pragma unroll
  for (int nt = 0; nt < 2; nt++) {
    int row = wn * 32 + nt * 16 + mrow;
    int sw = ((row >> 2) & 7) << 3;
#pragma unroll
    for (int kh = 0; kh < 2; kh++)
      broff[nt][kh] = row * 72 + ((kh * 32 + quad * 8) ^ sw);
  }

  f32x4 acc1[4][2], acc3[4][2];
#pragma unroll
  for (int mt = 0; mt < 4; mt++)
#pragma unroll
    for (int nt = 0; nt < 2; nt++) { acc1[mt][nt] = (f32x4)(0.f); acc3[mt][nt] = (f32x4)(0.f); }

  for (int kt = 0; kt < H_DIM; kt += 64) {
#pragma unroll
    for (int it = 0; it < 4; it++) {
      uint4 v = *reinterpret_cast<const uint4*>(aptr[it] + kt);
      *reinterpret_cast<uint4*>(&As[aoff[it]]) = v;
    }
    // B: 4 fp32 rows x 4 cols per matrix, pack K into b64, swizzled write
    float4 r1[4], r3[4];
    const float* g1 = gb1 + (long)kt * F_DIM;
    const float* g3 = gb3 + (long)kt * F_DIM;
#pragma unroll
    for (int kk = 0; kk < 4; kk++) {
      r1[kk] = *reinterpret_cast<const float4*>(g1 + (long)kk * F_DIM);
      r3[kk] = *reinterpret_cast<const float4*>(g3 + (long)kk * F_DIM);
    }
#pragma unroll
    for (int j = 0; j < 4; j++) {
      u32 lo1 = (u32)f2bf(((const float*)&r1[0])[j]) | ((u32)f2bf(((const float*)&r1[1])[j]) << 16);
      u32 hi1 = (u32)f2bf(((const float*)&r1[2])[j]) | ((u32)f2bf(((const float*)&r1[3])[j]) << 16);
      u32 lo3 = (u32)f2bf(((const float*)&r3[0])[j]) | ((u32)f2bf(((const float*)&r3[1])[j]) << 16);
      u32 hi3 = (u32)f2bf(((const float*)&r3[2])[j]) | ((u32)f2bf(((const float*)&r3[3])[j]) << 16);
      uint2 p1 = {lo1, hi1}, p3 = {lo3, hi3};
      *reinterpret_cast<uint2*>(&B1s[bwoff[j]]) = p1;
      *reinterpret_cast<uint2*>(&B3s[bwoff[j]]) = p3;
    }
    __syncthreads();
#pragma unroll
    for (int kh = 0; kh < 2; kh++) {
      bf16x8 af[4], b1f[2], b3f[2];
#pragma unroll
      for (int mt = 0; mt < 4; mt++)
        af[mt] = *reinterpret_cast<const bf16x8*>(&As[aroff[mt][kh]]);
#pragma unroll
      for (int nt = 0; nt < 2; nt++) {
        b1f[nt] = *reinterpret_cast<const bf16x8*>(&B1s[broff[nt][kh]]);
        b3f[nt] = *reinterpret_cast<const bf16x8*>(&B3s[broff[nt][kh]]);
      }
#pragma unroll
      for (int mt = 0; mt < 4; mt++)
#pragma unroll
        for (int nt = 0; nt < 2; nt++) {
          acc1[mt][nt] = __builtin_amdgcn_mfma_f32_16x16x32_bf16(af[mt], b1f[nt], acc1[mt][nt], 0, 0, 0);
          acc3[mt][nt] = __builtin_amdgcn_mfma_f32_16x16x32_bf16(af[mt], b3f[nt], acc3[mt][nt], 0, 0, 0);
        }
    }
    __syncthreads();
  }
  // epilogue: SwiGLU, write bf16 to compact rows; mask rows >= ne
  u16* hp = hout + (long)el * T_DIM * F_DIM;
#pragma unroll
  for (int mt = 0; mt < 4; mt++) {
#pragma unroll
    for (int r = 0; r < 4; r++) {
      int row = t0 + wm * 64 + mt * 16 + quad * 4 + r;
      if (row < ne) {
#pragma unroll
        for (int nt = 0; nt < 2; nt++) {
          int col = f0 + wn * 32 + nt * 16 + mrow;
          float v1 = acc1[mt][nt][r];
          float v3 = acc3[mt][nt][r];
          float sw = (v1 / (1.f + expf(-v1))) * v3;
          hp[(long)row * F_DIM + col] = f2bf(sw);
        }
      }
    }
  }
}

// ---------------------------------------------------------------------------
// Kernel 3: out[tok,:] += wts[tok,e] * (h_e @ w2[e]), compact rows.
// w2 read in NATIVE fp32 (F,H) layout, same fused transpose staging.
// ---------------------------------------------------------------------------
__global__ __launch_bounds__(256, 2) void y_kernel(
    const u16* __restrict__ h, const float* __restrict__ w2,
    const float* __restrict__ wts, float* __restrict__ out,
    const int* __restrict__ tlist, const int* __restrict__ counts) {
  int el = blockIdx.z;
  int ne = counts[el];
  int t0 = blockIdx.y * 128;
  if (t0 >= ne) return;

  __shared__ u16 As[128 * 72];
  __shared__ u16 Bs[64 * 72];
  int n0 = blockIdx.x * 64;
  const u16* a = h + (long)el * T_DIM * F_DIM;
  const float* b = w2 + (long)el * F_DIM * H_DIM;
  int tid = threadIdx.x;
  int wave = tid >> 6, lane = tid & 63;
  int wm = wave >> 1, wn = wave & 1;
  int mrow = lane & 15, quad = lane >> 4;

  int bh4 = (tid & 15) << 2;
  int bk0 = (tid >> 4) << 2;
  int bwoff[4];
#pragma unroll
  for (int j = 0; j < 4; j++) {
    int f = bh4 + j;
    bwoff[j] = f * 72 + (bk0 ^ (((f >> 2) & 7) << 3));
  }
  const float* gb = b + (long)bk0 * H_DIM + n0 + bh4;

  int aroff[4][2], broff[2][2];
#pragma unroll
  for (int mt = 0; mt < 4; mt++)
#pragma unroll
    for (int kh = 0; kh < 2; kh++)
      aroff[mt][kh] = (wm * 64 + mt * 16 + mrow) * 72 + kh * 32 + quad * 8;
#pragma unroll
  for (int nt = 0; nt < 2; nt++) {
    int row = wn * 32 + nt * 16 + mrow;
    int sw = ((row >> 2) & 7) << 3;
#pragma unroll
    for (int kh = 0; kh < 2; kh++)
      broff[nt][kh] = row * 72 + ((kh * 32 + quad * 8) ^ sw);
  }

  f32x4 acc[4][2];
#pragma unroll
  for (int mt = 0; mt < 4; mt++)
#pragma unroll
    for (int nt = 0; nt < 2; nt++) acc[mt][nt] = (f32x4)(0.f);

  for (int kt = 0; kt < F_DIM; kt += 64) {
#pragma unroll
    for (int it = 0; it < 4; it++) {
      int chunk = tid + it * 256;
      int r = chunk >> 3, c8 = (chunk & 7) << 3;
      uint4 v = *reinterpret_cast<const uint4*>(a + (long)(t0 + r) * F_DIM + kt + c8);
      *reinterpret_cast<uint4*>(&As[r * 72 + c8]) = v;
    }
    float4 rb[4];
    const float* g = gb + (long)kt * H_DIM;
#pragma unroll
    for (int kk = 0; kk < 4; kk++)
      rb[kk] = *reinterpret_cast<const float4*>(g + (long)kk * H_DIM);
#pragma unroll
    for (int j = 0; j < 4; j++) {
      u32 lo = (u32)f2bf(((const float*)&rb[0])[j]) | ((u32)f2bf(((const float*)&rb[1])[j]) << 16);
      u32 hi = (u32)f2bf(((const float*)&rb[2])[j]) | ((u32)f2bf(((const float*)&rb[3])[j]) << 16);
      uint2 pb = {lo, hi};
      *reinterpret_cast<uint2*>(&Bs[bwoff[j]]) = pb;
    }
    __syncthreads();
#pragma unroll
    for (int kh = 0; kh < 2; kh++) {
      bf16x8 af[4], bf[2];
#pragma unroll
      for (int mt = 0; mt < 4; mt++)
        af[mt] = *reinterpret_cast<const bf16x8*>(&As[aroff[mt][kh]]);
#pragma unroll
      for (int nt = 0; nt < 2; nt++)
        bf[nt] = *reinterpret_cast<const bf16x8*>(&Bs[broff[nt][kh]]);
#pragma unroll
      for (int mt = 0; mt < 4; mt++)
#pragma unroll
        for (int nt = 0; nt < 2; nt++)
          acc[mt][nt] = __builtin_amdgcn_mfma_f32_16x16x32_bf16(af[mt], bf[nt], acc[mt][nt], 0, 0, 0);
    }
    __syncthreads();
  }
#pragma unroll
  for (int mt = 0; mt < 4; mt++) {
#pragma unroll
    for (int r = 0; r < 4; r++) {
      int row = t0 + wm * 64 + mt * 16 + quad * 4 + r;
      if (row < ne) {
        int tok = tlist[el * T_DIM + row];
        float wt = wts[tok * 8 + el];
#pragma unroll
        for (int nt = 0; nt < 2; nt++) {
          int col = n0 + wn * 32 + nt * 16 + mrow;
          unsafeAtomicAdd(&out[(long)tok * H_DIM + col], acc[mt][nt][r] * wt);
        }
      }
    }
  }
}

// ---------------------------------------------------------------------------
extern "C" void kernel_launch(void* const* d_in, const int* in_sizes, int n_in,
                              void* d_out, int out_size, void* d_ws, size_t ws_size,
                              hipStream_t stream) {
  const float* x  = (const float*)d_in[0];
  const float* wg = (const float*)d_in[1];
  const float* w1 = (const float*)d_in[2];
  const float* w3 = (const float*)d_in[3];
  const float* w2 = (const float*)d_in[4];
  float* out = (float*)d_out;

  char* p = (char*)d_ws;
  u16* xb = (u16*)p;            p += (size_t)T_DIM * H_DIM * 2;
  float* wts = (float*)p;       p += (size_t)T_DIM * E_DIM * 4;
  int* tlist = (int*)p;         p += (size_t)E_DIM * T_DIM * 4;
  int* counts = (int*)p;        p += 256;
  u16* hbuf = (u16*)p;          // E * T * F bf16 (compact rows per expert)

  gate_cvt_kernel<<<T_DIM / 4, 256, 0, stream>>>(x, wg, xb, wts);
  route_kernel<<<1, 512, 0, stream>>>(wts, tlist, counts);
  hipMemsetAsync(d_out, 0, (size_t)out_size * 4, stream);

  h_kernel<<<dim3(F_DIM / 64, T_DIM / 128, E_DIM), 256, 0, stream>>>(
      xb, w1, w3, hbuf, tlist, counts);
  y_kernel<<<dim3(H_DIM / 64, T_DIM / 128, E_DIM), 256, 0, stream>>>(
      hbuf, w2, wts, out, tlist, counts);
}

// Round 3
// 822.317 us; speedup vs baseline: 1.5102x; 1.0955x over previous
//
#include <hip/hip_runtime.h>
#include <hip/hip_bf16.h>

#define T_DIM 1024
#define H_DIM 2048
#define F_DIM 4096
#define E_DIM 8

typedef unsigned short u16;
typedef unsigned int u32;
typedef __attribute__((ext_vector_type(8))) short bf16x8;
typedef __attribute__((ext_vector_type(4))) float f32x4;

// round-to-nearest-even fp32 -> bf16 (raw bits)
__device__ __forceinline__ u16 f2bf(float f) {
  u32 u = __builtin_bit_cast(u32, f);
  u32 r = (u + 0x7fffu + ((u >> 16) & 1u)) >> 16;
  return (u16)r;
}

// async global->LDS, 16B per lane; dest = wave-uniform base + lane*16
__device__ __forceinline__ void gld_lds16(const void* g, void* l) {
  __builtin_amdgcn_global_load_lds(
      (const __attribute__((address_space(1))) u32*)g,
      (__attribute__((address_space(3))) u32*)l, 16, 0, 0);
}

// raw workgroup barrier with compiler memory fences (no implicit vmcnt drain)
__device__ __forceinline__ void wg_barrier() {
  asm volatile("" ::: "memory");
  __builtin_amdgcn_s_barrier();
  asm volatile("" ::: "memory");
}

// ---------------------------------------------------------------------------
// Kernel 1: gate logits + top-2 weights (exact reference emulation) + x->bf16
// ---------------------------------------------------------------------------
__global__ __launch_bounds__(256) void gate_cvt_kernel(
    const float* __restrict__ x, const float* __restrict__ wg,
    u16* __restrict__ xb, float* __restrict__ wts) {
  int wave = threadIdx.x >> 6;
  int lane = threadIdx.x & 63;
  int t = blockIdx.x * 4 + wave;
  const float4* x4 = reinterpret_cast<const float4*>(x) + (size_t)t * 512;
  ushort4* xb4 = reinterpret_cast<ushort4*>(xb) + (size_t)t * 512;
  const float4* wg4 = reinterpret_cast<const float4*>(wg);

  float acc[8];
#pragma unroll
  for (int e = 0; e < 8; e++) acc[e] = 0.f;

#pragma unroll
  for (int i = 0; i < 8; i++) {
    int idx = i * 64 + lane;
    float4 v = x4[idx];
    ushort4 o = {f2bf(v.x), f2bf(v.y), f2bf(v.z), f2bf(v.w)};
    xb4[idx] = o;
    float xs[4] = {v.x, v.y, v.z, v.w};
    int hbase = idx * 4;
#pragma unroll
    for (int j = 0; j < 4; j++) {
      float4 wa = wg4[(hbase + j) * 2];
      float4 wb = wg4[(hbase + j) * 2 + 1];
      acc[0] += xs[j] * wa.x; acc[1] += xs[j] * wa.y;
      acc[2] += xs[j] * wa.z; acc[3] += xs[j] * wa.w;
      acc[4] += xs[j] * wb.x; acc[5] += xs[j] * wb.y;
      acc[6] += xs[j] * wb.z; acc[7] += xs[j] * wb.w;
    }
  }
#pragma unroll
  for (int e = 0; e < 8; e++) {
#pragma unroll
    for (int off = 32; off > 0; off >>= 1) acc[e] += __shfl_xor(acc[e], off, 64);
  }
  if (lane == 0) {
    const float NEG_MIN = -3.402823466e38f;
    float ex0 = acc[0];
#pragma unroll
    for (int e = 1; e < 8; e++) ex0 = fmaxf(ex0, acc[e]);
    float masked[8];
#pragma unroll
    for (int e = 0; e < 8; e++) masked[e] = (acc[e] == ex0) ? NEG_MIN : acc[e];
    float ex1 = masked[0];
#pragma unroll
    for (int e = 1; e < 8; e++) ex1 = fmaxf(ex1, masked[e]);
    float w0 = 1.f / (1.f + expf(ex1 - ex0));
#pragma unroll
    for (int e = 0; e < 8; e++) {
      float w = (acc[e] == ex0) ? w0 : ((masked[e] == ex1) ? (1.f - w0) : 0.f);
      wts[t * 8 + e] = w;
    }
  }
}

// ---------------------------------------------------------------------------
// Kernel 1b: deterministic per-expert token compaction (top-2 => wts!=0).
// ---------------------------------------------------------------------------
__global__ __launch_bounds__(512) void route_kernel(
    const float* __restrict__ wts, int* __restrict__ tlist,
    int* __restrict__ counts) {
  int e = threadIdx.x >> 6;
  int lane = threadIdx.x & 63;
  int base = 0;
  for (int c = 0; c < T_DIM; c += 64) {
    float w = wts[(c + lane) * 8 + e];
    unsigned long long m = __ballot(w != 0.f);
    if (w != 0.f) {
      int pos = base + __popcll(m & ((1ull << lane) - 1ull));
      tlist[e * T_DIM + pos] = c + lane;
    }
    base += __popcll(m);
  }
  if (lane == 0) counts[e] = base;
}

// ---------------------------------------------------------------------------
// Kernel 2: h_e = silu(xg @ w1[e]) * (xg @ w3[e]), bf16 out, compacted rows.
// 2-phase raw-barrier pipeline:
//   A: async global_load_lds, double-buffered, XOR-swizzled via pre-swizzled
//      global source (linear DMA dest), read with the same XOR.
//   B: fp32 strided loads -> regs (issued one tile ahead, in flight across the
//      raw barrier), fp32->bf16 pack, swizzled ds_write.
// Step: vmcnt(0); write B(i); issue A(i+1)+B(i+1); lgkmcnt(0); barrier;
//       MFMA(i); barrier.
// ---------------------------------------------------------------------------
__global__ __launch_bounds__(256, 3) void h_kernel(
    const u16* __restrict__ xb, const float* __restrict__ w1,
    const float* __restrict__ w3, u16* __restrict__ hout,
    const int* __restrict__ tlist, const int* __restrict__ counts) {
  int el = blockIdx.z;
  int ne = counts[el];
  int t0 = blockIdx.y * 128;
  if (t0 >= ne) return;

  __shared__ u16 As[2][128 * 64];
  __shared__ u16 B1s[64 * 72];
  __shared__ u16 B3s[64 * 72];
  __shared__ int toks[128];

  int f0 = blockIdx.x * 64;
  const float* b1 = w1 + (long)el * H_DIM * F_DIM;
  const float* b3 = w3 + (long)el * H_DIM * F_DIM;
  int tid = threadIdx.x;
  if (tid < 128) {
    int i = t0 + tid;
    toks[tid] = tlist[el * T_DIM + (i < ne ? i : ne - 1)];
  }
  __syncthreads();

  int wave = tid >> 6, lane = tid & 63;
  int wm = wave >> 1, wn = wave & 1;
  int mrow = lane & 15, quad = lane >> 4;

  // A staging: per-lane pre-swizzled global source, linear LDS dest
  const u16* asrc[4];
  int abase[4];
#pragma unroll
  for (int it = 0; it < 4; it++) {
    int chunk = tid + it * 256;
    int r = chunk >> 3, c8 = (chunk & 7) << 3;
    asrc[it] = xb + (long)toks[r] * H_DIM + (c8 ^ ((r & 7) << 3));
    abase[it] = (it * 256 + wave * 64) * 8;   // u16 index of wave-uniform base
  }

  // B staging coords: thread owns cols bf4..+3, k-rows bk0..+3
  int bf4 = (tid & 15) << 2;
  int bk0 = (tid >> 4) << 2;
  int bwoff[4];
#pragma unroll
  for (int j = 0; j < 4; j++) {
    int f = bf4 + j;
    bwoff[j] = f * 72 + (bk0 ^ (((f >> 2) & 7) << 3));
  }
  const float* gb1 = b1 + (long)bk0 * F_DIM + f0 + bf4;
  const float* gb3 = b3 + (long)bk0 * F_DIM + f0 + bf4;

  // fragment read offsets (XOR on both A and B reads)
  int aroff[4][2], broff[2][2];
#pragma unroll
  for (int mt = 0; mt < 4; mt++) {
    int row = wm * 64 + mt * 16 + mrow;
#pragma unroll
    for (int kh = 0; kh < 2; kh++)
      aroff[mt][kh] = row * 64 + ((kh * 32 + quad * 8) ^ ((row & 7) << 3));
  }
#pragma unroll
  for (int nt = 0; nt < 2; nt++) {
    int row = wn * 32 + nt * 16 + mrow;
    int sw = ((row >> 2) & 7) << 3;
#pragma unroll
    for (int kh = 0; kh < 2; kh++)
      broff[nt][kh] = row * 72 + ((kh * 32 + quad * 8) ^ sw);
  }

  f32x4 acc1[4][2], acc3[4][2];
#pragma unroll
  for (int mt = 0; mt < 4; mt++)
#pragma unroll
    for (int nt = 0; nt < 2; nt++) { acc1[mt][nt] = (f32x4)(0.f); acc3[mt][nt] = (f32x4)(0.f); }

  // prologue: tile 0 in flight
#pragma unroll
  for (int it = 0; it < 4; it++) gld_lds16(asrc[it], &As[0][abase[it]]);
  float4 r1[4], r3[4];
#pragma unroll
  for (int kk = 0; kk < 4; kk++) {
    r1[kk] = *reinterpret_cast<const float4*>(gb1 + (long)kk * F_DIM);
    r3[kk] = *reinterpret_cast<const float4*>(gb3 + (long)kk * F_DIM);
  }

  const int NT = H_DIM / 64;   // 32
#pragma unroll 2
  for (int i = 0; i < NT; i++) {
    int cur = i & 1;
    asm volatile("s_waitcnt vmcnt(0)" ::: "memory");   // A(i) DMA + B(i) regs done
    // pack + swizzled write B(i)
#pragma unroll
    for (int j = 0; j < 4; j++) {
      u32 lo1 = (u32)f2bf(((const float*)&r1[0])[j]) | ((u32)f2bf(((const float*)&r1[1])[j]) << 16);
      u32 hi1 = (u32)f2bf(((const float*)&r1[2])[j]) | ((u32)f2bf(((const float*)&r1[3])[j]) << 16);
      u32 lo3 = (u32)f2bf(((const float*)&r3[0])[j]) | ((u32)f2bf(((const float*)&r3[1])[j]) << 16);
      u32 hi3 = (u32)f2bf(((const float*)&r3[2])[j]) | ((u32)f2bf(((const float*)&r3[3])[j]) << 16);
      uint2 p1 = {lo1, hi1}, p3 = {lo3, hi3};
      *reinterpret_cast<uint2*>(&B1s[bwoff[j]]) = p1;
      *reinterpret_cast<uint2*>(&B3s[bwoff[j]]) = p3;
    }
    // issue tile i+1 (stays in flight across the raw barrier)
    if (i + 1 < NT) {
      long ko = (long)(i + 1) * 64;
#pragma unroll
      for (int it = 0; it < 4; it++) gld_lds16(asrc[it] + ko, &As[cur ^ 1][abase[it]]);
      long kf = ko * F_DIM;
#pragma unroll
      for (int kk = 0; kk < 4; kk++) {
        r1[kk] = *reinterpret_cast<const float4*>(gb1 + kf + (long)kk * F_DIM);
        r3[kk] = *reinterpret_cast<const float4*>(gb3 + kf + (long)kk * F_DIM);
      }
    }
    asm volatile("s_waitcnt lgkmcnt(0)" ::: "memory");  // B writes visible
    wg_barrier();
    // MFMA on As[cur], B1s/B3s
#pragma unroll
    for (int kh = 0; kh < 2; kh++) {
      bf16x8 af[4], b1f[2], b3f[2];
#pragma unroll
      for (int mt = 0; mt < 4; mt++)
        af[mt] = *reinterpret_cast<const bf16x8*>(&As[cur][aroff[mt][kh]]);
#pragma unroll
      for (int nt = 0; nt < 2; nt++) {
        b1f[nt] = *reinterpret_cast<const bf16x8*>(&B1s[broff[nt][kh]]);
        b3f[nt] = *reinterpret_cast<const bf16x8*>(&B3s[broff[nt][kh]]);
      }
#pragma unroll
      for (int mt = 0; mt < 4; mt++)
#pragma unroll
        for (int nt = 0; nt < 2; nt++) {
          acc1[mt][nt] = __builtin_amdgcn_mfma_f32_16x16x32_bf16(af[mt], b1f[nt], acc1[mt][nt], 0, 0, 0);
          acc3[mt][nt] = __builtin_amdgcn_mfma_f32_16x16x32_bf16(af[mt], b3f[nt], acc3[mt][nt], 0, 0, 0);
        }
    }
    wg_barrier();
  }
  // epilogue: SwiGLU, write bf16 to compact rows; mask rows >= ne
  u16* hp = hout + (long)el * T_DIM * F_DIM;
#pragma unroll
  for (int mt = 0; mt < 4; mt++) {
#pragma unroll
    for (int r = 0; r < 4; r++) {
      int row = t0 + wm * 64 + mt * 16 + quad * 4 + r;
      if (row < ne) {
#pragma unroll
        for (int nt = 0; nt < 2; nt++) {
          int col = f0 + wn * 32 + nt * 16 + mrow;
          float v1 = acc1[mt][nt][r];
          float v3 = acc3[mt][nt][r];
          float sw = (v1 / (1.f + expf(-v1))) * v3;
          hp[(long)row * F_DIM + col] = f2bf(sw);
        }
      }
    }
  }
}

// ---------------------------------------------------------------------------
// Kernel 3: out[tok,:] += wts[tok,e] * (h_e @ w2[e]), compact rows.
// Same 2-phase pipeline; A = compact h rows (bf16, glds), B = w2 fp32 strided.
// ---------------------------------------------------------------------------
__global__ __launch_bounds__(256, 3) void y_kernel(
    const u16* __restrict__ h, const float* __restrict__ w2,
    const float* __restrict__ wts, float* __restrict__ out,
    const int* __restrict__ tlist, const int* __restrict__ counts) {
  int el = blockIdx.z;
  int ne = counts[el];
  int t0 = blockIdx.y * 128;
  if (t0 >= ne) return;

  __shared__ u16 As[2][128 * 64];
  __shared__ u16 Bs[64 * 72];
  int n0 = blockIdx.x * 64;
  const u16* a = h + (long)el * T_DIM * F_DIM;
  const float* b = w2 + (long)el * F_DIM * H_DIM;
  int tid = threadIdx.x;
  int wave = tid >> 6, lane = tid & 63;
  int wm = wave >> 1, wn = wave & 1;
  int mrow = lane & 15, quad = lane >> 4;

  const u16* asrc[4];
  int abase[4];
#pragma unroll
  for (int it = 0; it < 4; it++) {
    int chunk = tid + it * 256;
    int r = chunk >> 3, c8 = (chunk & 7) << 3;
    asrc[it] = a + (long)(t0 + r) * F_DIM + (c8 ^ ((r & 7) << 3));
    abase[it] = (it * 256 + wave * 64) * 8;
  }

  int bh4 = (tid & 15) << 2;
  int bk0 = (tid >> 4) << 2;
  int bwoff[4];
#pragma unroll
  for (int j = 0; j < 4; j++) {
    int f = bh4 + j;
    bwoff[j] = f * 72 + (bk0 ^ (((f >> 2) & 7) << 3));
  }
  const float* gb = b + (long)bk0 * H_DIM + n0 + bh4;

  int aroff[4][2], broff[2][2];
#pragma unroll
  for (int mt = 0; mt < 4; mt++) {
    int row = wm * 64 + mt * 16 + mrow;
#pragma unroll
    for (int kh = 0; kh < 2; kh++)
      aroff[mt][kh] = row * 64 + ((kh * 32 + quad * 8) ^ ((row & 7) << 3));
  }
#pragma unroll
  for (int nt = 0; nt < 2; nt++) {
    int row = wn * 32 + nt * 16 + mrow;
    int sw = ((row >> 2) & 7) << 3;
#pragma unroll
    for (int kh = 0; kh < 2; kh++)
      broff[nt][kh] = row * 72 + ((kh * 32 + quad * 8) ^ sw);
  }

  f32x4 acc[4][2];
#pragma unroll
  for (int mt = 0; mt < 4; mt++)
#pragma unroll
    for (int nt = 0; nt < 2; nt++) acc[mt][nt] = (f32x4)(0.f);

  // prologue
#pragma unroll
  for (int it = 0; it < 4; it++) gld_lds16(asrc[it], &As[0][abase[it]]);
  float4 rb[4];
#pragma unroll
  for (int kk = 0; kk < 4; kk++)
    rb[kk] = *reinterpret_cast<const float4*>(gb + (long)kk * H_DIM);

  const int NT = F_DIM / 64;   // 64
#pragma unroll 2
  for (int i = 0; i < NT; i++) {
    int cur = i & 1;
    asm volatile("s_waitcnt vmcnt(0)" ::: "memory");
#pragma unroll
    for (int j = 0; j < 4; j++) {
      u32 lo = (u32)f2bf(((const float*)&rb[0])[j]) | ((u32)f2bf(((const float*)&rb[1])[j]) << 16);
      u32 hi = (u32)f2bf(((const float*)&rb[2])[j]) | ((u32)f2bf(((const float*)&rb[3])[j]) << 16);
      uint2 pb = {lo, hi};
      *reinterpret_cast<uint2*>(&Bs[bwoff[j]]) = pb;
    }
    if (i + 1 < NT) {
      long ko = (long)(i + 1) * 64;
#pragma unroll
      for (int it = 0; it < 4; it++) gld_lds16(asrc[it] + ko, &As[cur ^ 1][abase[it]]);
      long kf = ko * H_DIM;
#pragma unroll
      for (int kk = 0; kk < 4; kk++)
        rb[kk] = *reinterpret_cast<const float4*>(gb + kf + (long)kk * H_DIM);
    }
    asm volatile("s_waitcnt lgkmcnt(0)" ::: "memory");
    wg_barrier();
#pragma unroll
    for (int kh = 0; kh < 2; kh++) {
      bf16x8 af[4], bf[2];
#pragma unroll
      for (int mt = 0; mt < 4; mt++)
        af[mt] = *reinterpret_cast<const bf16x8*>(&As[cur][aroff[mt][kh]]);
#pragma unroll
      for (int nt = 0; nt < 2; nt++)
        bf[nt] = *reinterpret_cast<const bf16x8*>(&Bs[broff[nt][kh]]);
#pragma unroll
      for (int mt = 0; mt < 4; mt++)
#pragma unroll
        for (int nt = 0; nt < 2; nt++)
          acc[mt][nt] = __builtin_amdgcn_mfma_f32_16x16x32_bf16(af[mt], bf[nt], acc[mt][nt], 0, 0, 0);
    }
    wg_barrier();
  }
#pragma unroll
  for (int mt = 0; mt < 4; mt++) {
#pragma unroll
    for (int r = 0; r < 4; r++) {
      int row = t0 + wm * 64 + mt * 16 + quad * 4 + r;
      if (row < ne) {
        int tok = tlist[el * T_DIM + row];
        float wt = wts[tok * 8 + el];
#pragma unroll
        for (int nt = 0; nt < 2; nt++) {
          int col = n0 + wn * 32 + nt * 16 + mrow;
          unsafeAtomicAdd(&out[(long)tok * H_DIM + col], acc[mt][nt][r] * wt);
        }
      }
    }
  }
}

// ---------------------------------------------------------------------------
extern "C" void kernel_launch(void* const* d_in, const int* in_sizes, int n_in,
                              void* d_out, int out_size, void* d_ws, size_t ws_size,
                              hipStream_t stream) {
  const float* x  = (const float*)d_in[0];
  const float* wg = (const float*)d_in[1];
  const float* w1 = (const float*)d_in[2];
  const float* w3 = (const float*)d_in[3];
  const float* w2 = (const float*)d_in[4];
  float* out = (float*)d_out;

  char* p = (char*)d_ws;
  u16* xb = (u16*)p;            p += (size_t)T_DIM * H_DIM * 2;
  float* wts = (float*)p;       p += (size_t)T_DIM * E_DIM * 4;
  int* tlist = (int*)p;         p += (size_t)E_DIM * T_DIM * 4;
  int* counts = (int*)p;        p += 256;
  u16* hbuf = (u16*)p;          // E * T * F bf16 (compact rows per expert)

  gate_cvt_kernel<<<T_DIM / 4, 256, 0, stream>>>(x, wg, xb, wts);
  route_kernel<<<1, 512, 0, stream>>>(wts, tlist, counts);
  hipMemsetAsync(d_out, 0, (size_t)out_size * 4, stream);

  h_kernel<<<dim3(F_DIM / 64, T_DIM / 128, E_DIM), 256, 0, stream>>>(
      xb, w1, w3, hbuf, tlist, counts);
  y_kernel<<<dim3(H_DIM / 64, T_DIM / 128, E_DIM), 256, 0, stream>>>(
      hbuf, w2, wts, out, tlist, counts);
}